// Round 1
// baseline (33.369 us; speedup 1.0000x reference)
//
#include <hip/hip_runtime.h>
#include <math.h>

#define BB 4
#define MM 1024
#define NN 16384
#define KPB 8
#define TPB 256

__global__ __launch_bounds__(TPB) void knn_loss_kernel(
    const float* __restrict__ kp, const float* __restrict__ pc,
    const float* __restrict__ sn, float* __restrict__ accum)
{
    const int blocks_per_b = MM / KPB;            // 128
    const int b  = blockIdx.x / blocks_per_b;
    const int m0 = (blockIdx.x % blocks_per_b) * KPB;
    const int tid = threadIdx.x;

    const float* kpx = kp + (b*3 + 0)*MM;
    const float* kpy = kp + (b*3 + 1)*MM;
    const float* kpz = kp + (b*3 + 2)*MM;
    const float* pcx = pc + (b*3 + 0)*NN;
    const float* pcy = pc + (b*3 + 1)*NN;
    const float* pcz = pc + (b*3 + 2)*NN;

    float kx[KPB], ky[KPB], kz[KPB], k2[KPB];
    #pragma unroll
    for (int k = 0; k < KPB; ++k) {
        kx[k] = kpx[m0 + k];
        ky[k] = kpy[m0 + k];
        kz[k] = kpz[m0 + k];
        k2[k] = kx[k]*kx[k] + ky[k]*ky[k] + kz[k]*kz[k];
    }

    float bestd[KPB];
    int   besti[KPB];
    #pragma unroll
    for (int k = 0; k < KPB; ++k) { bestd[k] = INFINITY; besti[k] = 0; }

    // each thread: 4 consecutive points, stride TPB*4 = 1024. N/1024 = 16 iters.
    for (int n0 = tid * 4; n0 < NN; n0 += TPB * 4) {
        float4 x4 = *reinterpret_cast<const float4*>(pcx + n0);
        float4 y4 = *reinterpret_cast<const float4*>(pcy + n0);
        float4 z4 = *reinterpret_cast<const float4*>(pcz + n0);
        float pxs[4] = {x4.x, x4.y, x4.z, x4.w};
        float pys[4] = {y4.x, y4.y, y4.z, y4.w};
        float pzs[4] = {z4.x, z4.y, z4.z, z4.w};
        #pragma unroll
        for (int j = 0; j < 4; ++j) {
            const float px = pxs[j], py = pys[j], pz = pzs[j];
            const float p2 = px*px + py*py + pz*pz;
            const int n = n0 + j;
            #pragma unroll
            for (int k = 0; k < KPB; ++k) {
                float dot = fmaf(kx[k], px, fmaf(ky[k], py, kz[k]*pz));
                float d2  = fmaf(-2.0f, dot, k2[k] + p2);
                if (d2 < bestd[k]) { bestd[k] = d2; besti[k] = n; }  // strict <: first occurrence within thread
            }
        }
    }

    // wave-level shuffle min-reduce (64 lanes), idx tie-break -> smaller idx
    #pragma unroll
    for (int k = 0; k < KPB; ++k) {
        float d = bestd[k]; int i = besti[k];
        for (int off = 32; off > 0; off >>= 1) {
            float od = __shfl_down(d, off, 64);
            int   oi = __shfl_down(i, off, 64);
            if (od < d || (od == d && oi < i)) { d = od; i = oi; }
        }
        bestd[k] = d; besti[k] = i;
    }

    __shared__ float sd[TPB/64][KPB];
    __shared__ int   si[TPB/64][KPB];
    __shared__ float sloss[KPB];

    const int wave = tid >> 6, lane = tid & 63;
    if (lane == 0) {
        #pragma unroll
        for (int k = 0; k < KPB; ++k) { sd[wave][k] = bestd[k]; si[wave][k] = besti[k]; }
    }
    __syncthreads();

    if (tid < KPB) {
        const int k = tid;
        float d = sd[0][k]; int i = si[0][k];
        #pragma unroll
        for (int w = 1; w < TPB/64; ++w) {
            float od = sd[w][k]; int oi = si[w][k];
            if (od < d || (od == d && oi < i)) { d = od; i = oi; }
        }
        const int idx = i;
        // reload this keypoint's coords from global (avoid runtime-indexed reg arrays)
        const float kxx = kpx[m0 + k], kyy = kpy[m0 + k], kzz = kpz[m0 + k];
        const float px = pcx[idx], py = pcy[idx], pz = pcz[idx];
        const float* snx = sn + (b*3 + 0)*NN;
        const float* sny = sn + (b*3 + 1)*NN;
        const float* snz = sn + (b*3 + 2)*NN;
        const float sx = snx[idx], sy = sny[idx], sz = snz[idx];
        const float dx = kxx - px, dy = kyy - py, dz = kzz - pz;
        const float dn = sqrtf(dx*dx + dy*dy + dz*dz);
        const float inv = 1.0f / (dn + 1e-7f);
        const float dot = (sx*dx + sy*dy + sz*dz) * inv;
        sloss[k] = dot * dot;
    }
    __syncthreads();

    if (tid == 0) {
        float s = 0.0f;
        #pragma unroll
        for (int k = 0; k < KPB; ++k) s += sloss[k];
        atomicAdd(accum, s);
    }
}

__global__ void finalize_kernel(const float* __restrict__ accum, float* __restrict__ out)
{
    out[0] = accum[0] * (1.0f / (float)(BB * MM));
}

extern "C" void kernel_launch(void* const* d_in, const int* in_sizes, int n_in,
                              void* d_out, int out_size, void* d_ws, size_t ws_size,
                              hipStream_t stream) {
    const float* kp = (const float*)d_in[0];
    const float* pc = (const float*)d_in[1];
    const float* sn = (const float*)d_in[2];
    float* out = (float*)d_out;
    float* accum = (float*)d_ws;

    hipMemsetAsync(accum, 0, sizeof(float), stream);

    const int nblocks = BB * (MM / KPB);   // 512
    knn_loss_kernel<<<nblocks, TPB, 0, stream>>>(kp, pc, sn, accum);
    finalize_kernel<<<1, 1, 0, stream>>>(accum, out);
}

// Round 2
// 30.893 us; speedup vs baseline: 1.0802x; 1.0802x over previous
//
#include <hip/hip_runtime.h>
#include <math.h>

#define BB 4
#define MM 1024
#define NN 16384
#define KPB 8
#define TPB 256
#define NSPLIT 4
#define NSEG (NN / NSPLIT)                    // 4096 points per block
#define BLOCKS_PER_B ((MM / KPB) * NSPLIT)    // 512

typedef unsigned int u32;
typedef unsigned long long u64;

__device__ __forceinline__ u32 ord_f32(float x) {
    u32 f = __float_as_uint(x);
    return f ^ ((u32)((int)f >> 31) | 0x80000000u);   // monotone float->uint map
}

__global__ __launch_bounds__(TPB, 4) void knn_kernel(
    const float* __restrict__ kp, const float* __restrict__ pc,
    u64* __restrict__ keys)
{
    const int b   = blockIdx.x / BLOCKS_PER_B;
    const int rem = blockIdx.x % BLOCKS_PER_B;
    const int m0  = (rem / NSPLIT) * KPB;
    const int seg = rem % NSPLIT;
    const int nbase = seg * NSEG;
    const int tid = threadIdx.x;

    const float* kpx = kp + (b*3 + 0)*MM;
    const float* kpy = kp + (b*3 + 1)*MM;
    const float* kpz = kp + (b*3 + 2)*MM;
    const float* pcx = pc + (b*3 + 0)*NN;
    const float* pcy = pc + (b*3 + 1)*NN;
    const float* pcz = pc + (b*3 + 2)*NN;

    float m2x[KPB], m2y[KPB], m2z[KPB], k2[KPB];
    #pragma unroll
    for (int k = 0; k < KPB; ++k) {
        const float kx = kpx[m0 + k], ky = kpy[m0 + k], kz = kpz[m0 + k];
        m2x[k] = -2.0f * kx; m2y[k] = -2.0f * ky; m2z[k] = -2.0f * kz;
        k2[k]  = kx*kx + ky*ky + kz*kz;
    }

    float bestd[KPB];
    int   besti[KPB];
    #pragma unroll
    for (int k = 0; k < KPB; ++k) { bestd[k] = INFINITY; besti[k] = 0; }

    // 4 iterations: each thread takes 4 consecutive points, stride 1024
    for (int n0 = nbase + tid * 4; n0 < nbase + NSEG; n0 += TPB * 4) {
        float4 x4 = *reinterpret_cast<const float4*>(pcx + n0);
        float4 y4 = *reinterpret_cast<const float4*>(pcy + n0);
        float4 z4 = *reinterpret_cast<const float4*>(pcz + n0);
        float pxs[4] = {x4.x, x4.y, x4.z, x4.w};
        float pys[4] = {y4.x, y4.y, y4.z, y4.w};
        float pzs[4] = {z4.x, z4.y, z4.z, z4.w};
        #pragma unroll
        for (int j = 0; j < 4; ++j) {
            const float px = pxs[j], py = pys[j], pz = pzs[j];
            const float p2 = px*px + py*py + pz*pz;
            const int n = n0 + j;
            #pragma unroll
            for (int k = 0; k < KPB; ++k) {
                const float d2 = fmaf(m2x[k], px,
                                 fmaf(m2y[k], py,
                                 fmaf(m2z[k], pz, k2[k] + p2)));
                if (d2 < bestd[k]) { bestd[k] = d2; besti[k] = n; }  // strict <: first n wins
            }
        }
    }

    // pack (ordered d2, n); u64 min == (min d2, tie -> min n)
    #pragma unroll
    for (int k = 0; k < KPB; ++k) {
        u64 key = ((u64)ord_f32(bestd[k]) << 32) | (u32)besti[k];
        #pragma unroll
        for (int off = 32; off > 0; off >>= 1) {
            u64 o = __shfl_down(key, off, 64);
            if (o < key) key = o;
        }
        if ((tid & 63) == 0)
            atomicMin(&keys[b*MM + m0 + k], key);
    }
}

__global__ __launch_bounds__(TPB) void loss_kernel(
    const float* __restrict__ kp, const float* __restrict__ pc,
    const float* __restrict__ sn, const u64* __restrict__ keys,
    float* __restrict__ out)
{
    const int gid = blockIdx.x * TPB + threadIdx.x;   // 0..4095
    const int b = gid / MM, m = gid % MM;

    const int idx = (int)(keys[gid] & 0xFFFFFFFFull);

    const float kx = kp[(b*3+0)*MM + m];
    const float ky = kp[(b*3+1)*MM + m];
    const float kz = kp[(b*3+2)*MM + m];
    const float px = pc[(b*3+0)*NN + idx];
    const float py = pc[(b*3+1)*NN + idx];
    const float pz = pc[(b*3+2)*NN + idx];
    const float sx = sn[(b*3+0)*NN + idx];
    const float sy = sn[(b*3+1)*NN + idx];
    const float sz = sn[(b*3+2)*NN + idx];

    const float dx = kx - px, dy = ky - py, dz = kz - pz;
    const float dn = sqrtf(dx*dx + dy*dy + dz*dz);
    const float inv = 1.0f / (dn + 1e-7f);
    const float dot = (sx*dx + sy*dy + sz*dz) * inv;
    float loss = dot * dot * (1.0f / (float)(BB * MM));

    #pragma unroll
    for (int off = 32; off > 0; off >>= 1)
        loss += __shfl_down(loss, off, 64);

    __shared__ float wsum[TPB / 64];
    const int wave = threadIdx.x >> 6, lane = threadIdx.x & 63;
    if (lane == 0) wsum[wave] = loss;
    __syncthreads();
    if (threadIdx.x == 0) {
        float s = 0.0f;
        #pragma unroll
        for (int w = 0; w < TPB / 64; ++w) s += wsum[w];
        atomicAdd(out, s);
    }
}

extern "C" void kernel_launch(void* const* d_in, const int* in_sizes, int n_in,
                              void* d_out, int out_size, void* d_ws, size_t ws_size,
                              hipStream_t stream) {
    const float* kp = (const float*)d_in[0];
    const float* pc = (const float*)d_in[1];
    const float* sn = (const float*)d_in[2];
    float* out = (float*)d_out;
    u64* keys = (u64*)d_ws;

    hipMemsetAsync(keys, 0xFF, (size_t)BB * MM * sizeof(u64), stream);  // UINT64_MAX
    hipMemsetAsync(out, 0, sizeof(float), stream);

    knn_kernel<<<BB * BLOCKS_PER_B, TPB, 0, stream>>>(kp, pc, keys);
    loss_kernel<<<(BB * MM) / TPB, TPB, 0, stream>>>(kp, pc, sn, keys, out);
}